// Round 3
// baseline (270.824 us; speedup 1.0000x reference)
//
#include <hip/hip_runtime.h>
#include <stdint.h>

typedef __bf16 bf16x8 __attribute__((ext_vector_type(8)));
typedef float f32x4 __attribute__((ext_vector_type(4)));

static constexpr float QK_SCALE = 0.044194173824159216f; // 1/sqrt(512)

__device__ __forceinline__ uint16_t f2bf(float f) {
    uint32_t x = __builtin_bit_cast(uint32_t, f);
    x += 0x7FFFu + ((x >> 16) & 1u);     // round-to-nearest-even; inputs finite
    return (uint16_t)(x >> 16);
}

// async 16B global->LDS copy (global_load_lds_dwordx4). LDS dest is
// wave-uniform base + lane*16; lds ptr = region_base + lane*16 matches.
__device__ __forceinline__ void cp16(const uint16_t* g, uint16_t* l) {
    __builtin_amdgcn_global_load_lds(
        (__attribute__((address_space(1))) void*)(uint16_t*)g,
        (__attribute__((address_space(3))) void*)l,
        16, 0, 0);
}

// ---------------------------------------------------------------------------
// NT GEMM: C[M,N] = A[M,K] * B[N,K]^T  (both K-contiguous, bf16)
// 128x128 block tile, BK=32, 256 thr = 4 waves (2x2), 64x64/wave.
// 3-stage circular LDS pipeline (3 x 16 KB = 48 KB) -> 3 blocks/CU.
// K-loop: RAW s_barrier + s_waitcnt vmcnt(4): stage k+1 and the just-issued
// k+2 stay in flight across the barrier. XOR-swizzled 16B chunks (0 bank
// conflicts, verified). XCD supertile swizzle. Tail prefetch clamps.
// MFMA operands swapped -> C^T layout -> packed dwordx2/x4 stores.
// MODE 0: bf16 out, batched, scale, no bias
// MODE 2: f32 out + bias0 (final projection)
// MODE 3: QKV split epilogue: n<512 -> Q, <1024 -> K, else V transposed
// MODE 5: bf16 out = acc / rowsum(A) (PV; softmax denominator folded in)
// ---------------------------------------------------------------------------
template <int MODE>
__global__ __launch_bounds__(256, 3) void gemm_nt(
    const uint16_t* __restrict__ A, const uint16_t* __restrict__ Bm,
    void* __restrict__ C0, void* __restrict__ C1, void* __restrict__ C2,
    const float* __restrict__ bias0, const float* __restrict__ bias1,
    const float* __restrict__ bias2,
    float scale, int K, int ldc, long bsA, long bsB, long bsC,
    int scols, int stPerBatch)
{
    // 3 stages x (A 128x32 | B 128x32) = 3 x 16 KB
    __shared__ __align__(16) uint16_t SH[3][8192];

    // --- supertile decode: id -> (bm, bn, bz) ------------------------------
    const uint32_t id  = blockIdx.x;
    const uint32_t xcd = id & 7u;
    const uint32_t p   = id >> 3;          // per-XCD sequence
    const uint32_t q   = p >> 4;           // local supertile index
    const uint32_t w   = p & 15u;          // position within 4x4 supertile
    const uint32_t g   = q * 8u + xcd;     // global supertile id
    const uint32_t bz  = g / (uint32_t)stPerBatch;
    const uint32_t gs  = g - bz * (uint32_t)stPerBatch;
    const uint32_t sr  = gs / (uint32_t)scols;
    const uint32_t sc  = gs - sr * (uint32_t)scols;
    const int bm = (int)(sr * 4u + (w >> 2));
    const int bn = (int)(sc * 4u + (w & 3u));
    // -----------------------------------------------------------------------

    const int t  = threadIdx.x;
    const int wave = t >> 6, lane = t & 63;
    const int wm = (wave >> 1) * 64, wn = (wave & 1) * 64;
    const int lm = lane & 15, lq = lane >> 4;
    const int sw = lq ^ ((lm >> 1) & 3);          // read-side swizzled k-group

    const uint16_t* Ab = A  + (long)bz * bsA + (long)bm * 128 * K;
    const uint16_t* Bb = Bm + (long)bz * bsB + (long)bn * 128 * K;

    // staging map (verified): slot s=j*256+t, row r=s>>2, slot col cs=s&3,
    // fetched k-group cg = cs ^ ((r>>1)&3); LDS addr = base + lane*16 (legal).
    long goff[2]; int loff[2];
#pragma unroll
    for (int j = 0; j < 2; ++j) {
        const int s  = j * 256 + t;
        const int r  = s >> 2;
        const int cs = s & 3;
        const int cg = cs ^ ((r >> 1) & 3);
        goff[j] = (long)r * K + cg * 8;
        loff[j] = s * 8;
    }

    const int KI = K >> 5;

    // prologue: stages 0,1 in flight (8 cp16/thread outstanding)
#pragma unroll
    for (int st = 0; st < 2; ++st)
#pragma unroll
        for (int j = 0; j < 2; ++j) {
            cp16(Ab + goff[j] + st * 32, SH[st] + loff[j]);
            cp16(Bb + goff[j] + st * 32, SH[st] + 4096 + loff[j]);
        }

    f32x4 acc[4][4] = {};
    float rsum[4] = {0.f, 0.f, 0.f, 0.f};         // MODE 5 only (else DCE'd)

    int cur = 0, pf = 2;                          // buf k%3, (k+2)%3
    for (int k = 0; k < KI; ++k) {
        asm volatile("s_waitcnt vmcnt(4) lgkmcnt(0)\n\ts_barrier" ::: "memory");

        int kp = k + 2; if (kp >= KI) kp = KI - 1; // tail: refetch hot tile
        uint16_t* dst = SH[pf];
        const long ko = (long)kp * 32;
#pragma unroll
        for (int j = 0; j < 2; ++j) {
            cp16(Ab + goff[j] + ko, dst + loff[j]);
            cp16(Bb + goff[j] + ko, dst + 4096 + loff[j]);
        }

        const uint16_t* buf = SH[cur];
        bf16x8 af[4], bfr[4];
#pragma unroll
        for (int i = 0; i < 4; ++i)               // A rows wm+i*16+lm
            af[i]  = *(const bf16x8*)&buf[((wm + i * 16 + lm) * 4 + sw) * 8];
#pragma unroll
        for (int i = 0; i < 4; ++i)               // B cols wn+i*16+lm
            bfr[i] = *(const bf16x8*)&buf[4096 + ((wn + i * 16 + lm) * 4 + sw) * 8];

        if (MODE == 5) {
            // rowsum of the A-fragments (bf16 -> f32 exact): this lane holds
            // rows wm+j*16+lm, k-slice sw*8..sw*8+7 of this K-step.
#pragma unroll
            for (int j = 0; j < 4; ++j) {
                const uint4 u = __builtin_bit_cast(uint4, af[j]);
                float s0 = __builtin_bit_cast(float, u.x << 16)
                         + __builtin_bit_cast(float, u.x & 0xFFFF0000u);
                float s1 = __builtin_bit_cast(float, u.y << 16)
                         + __builtin_bit_cast(float, u.y & 0xFFFF0000u);
                float s2 = __builtin_bit_cast(float, u.z << 16)
                         + __builtin_bit_cast(float, u.z & 0xFFFF0000u);
                float s3 = __builtin_bit_cast(float, u.w << 16)
                         + __builtin_bit_cast(float, u.w & 0xFFFF0000u);
                rsum[j] += (s0 + s1) + (s2 + s3);
            }
        }

#pragma unroll
        for (int i = 0; i < 4; ++i)
#pragma unroll
            for (int j = 0; j < 4; ++j)           // SWAPPED: D = C^T tile
                acc[i][j] = __builtin_amdgcn_mfma_f32_16x16x32_bf16(
                    bfr[i], af[j], acc[i][j], 0, 0, 0);

        cur = (cur == 2) ? 0 : cur + 1;
        pf  = (pf  == 2) ? 0 : pf  + 1;
    }

    // MODE 5: complete rowsum: lanes lm+16*lq (lq=0..3) hold disjoint
    // k-slices of the same A-row -> butterfly over lane bits 4,5.
    float inv[4];
    if (MODE == 5) {
#pragma unroll
        for (int j = 0; j < 4; ++j) {
            float s = rsum[j];
            s += __shfl_xor(s, 16);
            s += __shfl_xor(s, 32);
            inv[j] = 1.f / s;
        }
    }

    // epilogue: C^T layout -> lane holds n = nb+i*16+r (r=0..3 consecutive),
    // m = mb+j*16. Packed 8B/16B stores.
    const int mb = bm * 128 + wm + lm;
    const int nb = bn * 128 + wn + lq * 4;
#pragma unroll
    for (int i = 0; i < 4; ++i) {
        const int n = nb + i * 16;
        if (MODE == 0 || MODE == 5) {
#pragma unroll
            for (int j = 0; j < 4; ++j) {
                const int m = mb + j * 16;
                float v0, v1, v2, v3;
                if (MODE == 5) {                   // normalize by A-rowsum
                    v0 = acc[i][j][0] * inv[j];
                    v1 = acc[i][j][1] * inv[j];
                    v2 = acc[i][j][2] * inv[j];
                    v3 = acc[i][j][3] * inv[j];
                } else {
                    v0 = acc[i][j][0] * scale;
                    v1 = acc[i][j][1] * scale;
                    v2 = acc[i][j][2] * scale;
                    v3 = acc[i][j][3] * scale;
                }
                const uint32_t lo = (uint32_t)f2bf(v0) | ((uint32_t)f2bf(v1) << 16);
                const uint32_t hi = (uint32_t)f2bf(v2) | ((uint32_t)f2bf(v3) << 16);
                *(uint2*)&((uint16_t*)C0)[(long)bz * bsC + (long)m * ldc + n] =
                    make_uint2(lo, hi);
            }
        } else if (MODE == 2) {
            const float4 b4 = *(const float4*)&bias0[n];
#pragma unroll
            for (int j = 0; j < 4; ++j) {
                const int m = mb + j * 16;
                *(float4*)&((float*)C0)[(long)m * ldc + n] = make_float4(
                    acc[i][j][0] + b4.x, acc[i][j][1] + b4.y,
                    acc[i][j][2] + b4.z, acc[i][j][3] + b4.w);
            }
        } else { // MODE 3: whole block lives in one section (bn-uniform)
            const int sec = n >> 9, nn = n & 511;
            const float* bp = sec == 0 ? bias0 : (sec == 1 ? bias1 : bias2);
            const float4 b4 = *(const float4*)&bp[nn];
#pragma unroll
            for (int j = 0; j < 4; ++j) {
                const int m = mb + j * 16;
                if (sec < 2) {
                    uint16_t* Cq = (uint16_t*)(sec == 0 ? C0 : C1);
                    const uint32_t lo = (uint32_t)f2bf(acc[i][j][0] + b4.x) |
                                        ((uint32_t)f2bf(acc[i][j][1] + b4.y) << 16);
                    const uint32_t hi = (uint32_t)f2bf(acc[i][j][2] + b4.z) |
                                        ((uint32_t)f2bf(acc[i][j][3] + b4.w) << 16);
                    *(uint2*)&Cq[(long)m * 512 + nn] = make_uint2(lo, hi);
                } else { // V transposed: Vt[b][d][s], d = nn+r, s = m
                    const int bb = m >> 11, ss = m & 2047;
                    uint16_t* vt = (uint16_t*)C2 + ((long)bb * 512 + nn) * 2048 + ss;
                    vt[0]        = f2bf(acc[i][j][0] + b4.x);
                    vt[2048]     = f2bf(acc[i][j][1] + b4.y);
                    vt[2 * 2048] = f2bf(acc[i][j][2] + b4.z);
                    vt[3 * 2048] = f2bf(acc[i][j][3] + b4.w);
                }
            }
        }
    }
}

// ---------------------------------------------------------------------------
// R9: 256x256 / 8-wave / 4-phase NT GEMM, m201-ordered phases.
// R8 post-mortem: barrier AFTER the MFMA cluster hides nothing -- each phase
// exposed the full LDS-read drain (8 waves burst into one LDS pipe, MFMA
// waits on its own reads). m201's proven ordering puts the barrier BETWEEN
// the read burst and the MFMA cluster: the barrier-wait for the other waves
// absorbs the read latency, and the MFMA cluster then issues back-to-back.
// Phase = {ds_read frags | cp16 issue | s_barrier | (lgkm waits) | setprio(1)
// 8 MFMA setprio(0)}. No trailing barrier: a fast wave's next-phase reads
// overlap slower waves' MFMA (different pipes; cp16s target stage k+2 which
// is only read 2 iters later, behind the publish guard).
// Publish guard (vmcnt(4)+lgkmcnt(0)+barrier) at iter end, counting
// unchanged: 4 cp16/thread/iter -> vmcnt(4) == "stage k+1 fully landed".
// WAR safe: MFMA8(3)'s operand waits retire all 12 reads in-order before the
// end barrier; overwriting cp16s issue only after it.
// MODE 4: bf16 out = exp(acc*scale) (QK^T -> unnormalized P).
// ---------------------------------------------------------------------------
template <int MODE>
__global__ __launch_bounds__(512, 2) void gemm_nt8(
    const uint16_t* __restrict__ A, const uint16_t* __restrict__ Bm,
    void* __restrict__ C0,
    float scale, int K, int ldc, long bsA, long bsB, long bsC,
    int scols, int stPerBatch)
{
    // 3 stages x (A 256x32 | B 256x32) = 3 x 32 KB = 96 KB -> 1 block/CU
    __shared__ __align__(16) uint16_t SH[3][16384];

    // --- supertile decode (4x4 of 256^2 tiles), XCD-chunked ----------------
    const uint32_t id  = blockIdx.x;
    const uint32_t xcd = id & 7u;
    const uint32_t p   = id >> 3;
    const uint32_t q   = p >> 4;
    const uint32_t w   = p & 15u;
    const uint32_t g   = q * 8u + xcd;
    const uint32_t bz  = g / (uint32_t)stPerBatch;
    const uint32_t gs  = g - bz * (uint32_t)stPerBatch;
    const uint32_t sr  = gs / (uint32_t)scols;
    const uint32_t sc  = gs - sr * (uint32_t)scols;
    const int bm = (int)(sr * 4u + (w >> 2));
    const int bn = (int)(sc * 4u + (w & 3u));
    // -----------------------------------------------------------------------

    const int t  = threadIdx.x;
    const int wave = t >> 6, lane = t & 63;
    const int wm2 = (wave >> 2) * 128;            // row half   (0,128)
    const int wn2 = (wave & 3) * 64;              // col quarter(0..192)
    const int lm = lane & 15, lq = lane >> 4;
    const int sw = lq ^ ((lm >> 1) & 3);          // read-side swizzled k-group

    const uint16_t* Ab = A  + (long)bz * bsA + (long)bm * 256 * K;
    const uint16_t* Bb = Bm + (long)bz * bsB + (long)bn * 256 * K;

    // staging map (same verified XOR scheme, 256 rows x 4 chunks = 1024 slots
    // of 16B per operand, 512 threads -> 2 slots/thread/operand)
    long goff[2]; int loff[2];
#pragma unroll
    for (int j = 0; j < 2; ++j) {
        const int s  = j * 512 + t;
        const int r  = s >> 2;
        const int cs = s & 3;
        const int cg = cs ^ ((r >> 1) & 3);
        goff[j] = (long)r * K + cg * 8;
        loff[j] = s * 8;
    }

    const int KI = K >> 5;

    // prologue: stages 0,1 in flight (8 cp16/thread outstanding), then
    // publish stage 0 (vmcnt(4): stage 1's 4 remain in flight).
#pragma unroll
    for (int st = 0; st < 2; ++st)
#pragma unroll
        for (int j = 0; j < 2; ++j) {
            cp16(Ab + goff[j] + st * 32, SH[st] + loff[j]);
            cp16(Bb + goff[j] + st * 32, SH[st] + 8192 + loff[j]);
        }
    asm volatile("s_waitcnt vmcnt(4)\n\ts_barrier" ::: "memory");

    f32x4 acc[4][8] = {};

    int cur = 0, pf = 2;
    for (int k = 0; k < KI; ++k) {
        int kp = k + 2; if (kp >= KI) kp = KI - 1;
        uint16_t* dst = SH[pf];
        const long ko = (long)kp * 32;
        const uint16_t* buf = SH[cur];

        bf16x8 af[8], bfr[4];
#define RDA(jj) (*(const bf16x8*)&buf[((wm2 + (jj) * 16 + lm) * 4 + sw) * 8])
#define RDB(ii) (*(const bf16x8*)&buf[8192 + ((wn2 + (ii) * 16 + lm) * 4 + sw) * 8])
#define MFMA8(pp)                                                              \
    __builtin_amdgcn_s_setprio(1);                                             \
    _Pragma("unroll")                                                          \
    for (int i = 0; i < 4; ++i) {                                              \
        acc[i][2 * (pp)]     = __builtin_amdgcn_mfma_f32_16x16x32_bf16(        \
            bfr[i], af[2 * (pp)],     acc[i][2 * (pp)],     0, 0, 0);          \
        acc[i][2 * (pp) + 1] = __builtin_amdgcn_mfma_f32_16x16x32_bf16(        \
            bfr[i], af[2 * (pp) + 1], acc[i][2 * (pp) + 1], 0, 0, 0);          \
    }                                                                          \
    __builtin_amdgcn_s_setprio(0);

        // ---- phase 0: reads (all B + A0,A1) | stage A#0 | barrier | mfma --
        bfr[0] = RDB(0); bfr[1] = RDB(1); bfr[2] = RDB(2); bfr[3] = RDB(3);
        af[0] = RDA(0); af[1] = RDA(1);
        cp16(Ab + goff[0] + ko, dst + loff[0]);
        asm volatile("s_barrier" ::: "memory");
        MFMA8(0);
        // ---- phase 1: reads A2,A3 | stage A#1 | barrier | mfma ----
        af[2] = RDA(2); af[3] = RDA(3);
        cp16(Ab + goff[1] + ko, dst + loff[1]);
        asm volatile("s_barrier" ::: "memory");
        MFMA8(1);
        // ---- phase 2: reads A4,A5 | stage B#0 | barrier | mfma ----
        af[4] = RDA(4); af[5] = RDA(5);
        cp16(Bb + goff[0] + ko, dst + 8192 + loff[0]);
        asm volatile("s_barrier" ::: "memory");
        MFMA8(2);
        // ---- phase 3: reads A6,A7 | stage B#1 | barrier | mfma ----
        af[6] = RDA(6); af[7] = RDA(7);
        cp16(Bb + goff[1] + ko, dst + 8192 + loff[1]);
        asm volatile("s_barrier" ::: "memory");
        MFMA8(3);
        // ---- publish stage k+1 for next iter's phase-0 reads ----
        asm volatile("s_waitcnt vmcnt(4) lgkmcnt(0)\n\ts_barrier" ::: "memory");
#undef RDA
#undef RDB
#undef MFMA8

        cur = (cur == 2) ? 0 : cur + 1;
        pf  = (pf  == 2) ? 0 : pf  + 1;
    }

    // epilogue: C^T layout; m = row (lane&15 based), n = col (lq*4+reg based)
    const int mb = bm * 256 + wm2 + lm;
    const int nb = bn * 256 + wn2 + lq * 4;
#pragma unroll
    for (int i = 0; i < 4; ++i) {
        const int n = nb + i * 16;
#pragma unroll
        for (int j = 0; j < 8; ++j) {
            const int m = mb + j * 16;
            float v0, v1, v2, v3;
            if (MODE == 4) {                       // unnormalized softmax num.
                v0 = __expf(acc[i][j][0] * scale);
                v1 = __expf(acc[i][j][1] * scale);
                v2 = __expf(acc[i][j][2] * scale);
                v3 = __expf(acc[i][j][3] * scale);
            } else {
                v0 = acc[i][j][0] * scale; v1 = acc[i][j][1] * scale;
                v2 = acc[i][j][2] * scale; v3 = acc[i][j][3] * scale;
            }
            const uint32_t lo = (uint32_t)f2bf(v0) | ((uint32_t)f2bf(v1) << 16);
            const uint32_t hi = (uint32_t)f2bf(v2) | ((uint32_t)f2bf(v3) << 16);
            *(uint2*)&((uint16_t*)C0)[(long)bz * bsC + (long)m * ldc + n] =
                make_uint2(lo, hi);
        }
    }
}

// x + pos_table -> bf16, 8 elems/thread, exact grid (4096 blocks)
__global__ __launch_bounds__(256) void prep_x(const float* __restrict__ x,
                                              const float* __restrict__ pos,
                                              uint16_t* __restrict__ xb)
{
    const long i8 = ((long)blockIdx.x * 256 + threadIdx.x) * 8;
    const long p8 = i8 & ((1l << 20) - 1);   // S*D = 2^20
    const float4* xv = (const float4*)(x + i8);
    const float4* pv = (const float4*)(pos + p8);
    const float4 a0 = xv[0], a1 = xv[1];
    const float4 b0 = pv[0], b1 = pv[1];
    uint16_t o[8];
    o[0] = f2bf(a0.x + b0.x); o[1] = f2bf(a0.y + b0.y);
    o[2] = f2bf(a0.z + b0.z); o[3] = f2bf(a0.w + b0.w);
    o[4] = f2bf(a1.x + b1.x); o[5] = f2bf(a1.y + b1.y);
    o[6] = f2bf(a1.z + b1.z); o[7] = f2bf(a1.w + b1.w);
    *(uint4*)(xb + i8) = *(uint4*)o;
}

// Wq,Wk,Wv -> stacked wqkv[1536,512] bf16; Wd -> wd bf16. 512 blocks exact.
__global__ __launch_bounds__(256) void prep_w(
    const float* __restrict__ Wq, const float* __restrict__ Wk,
    const float* __restrict__ Wv, const float* __restrict__ Wd,
    uint16_t* __restrict__ wqkv, uint16_t* __restrict__ wd)
{
    const long f = ((long)blockIdx.x * 256 + threadIdx.x) * 8;
    const int  w = (int)(f >> 18);          // 262144 elems per weight
    const long off = f & 262143;
    const float* src = (w == 0) ? Wq : (w == 1) ? Wk : (w == 2) ? Wv : Wd;
    uint16_t* dst = (w < 3) ? (wqkv + (long)w * 262144 + off) : (wd + off);
    const float4* s4 = (const float4*)(src + off);
    const float4 a = s4[0], b = s4[1];
    uint16_t o[8];
    o[0] = f2bf(a.x); o[1] = f2bf(a.y); o[2] = f2bf(a.z); o[3] = f2bf(a.w);
    o[4] = f2bf(b.x); o[5] = f2bf(b.y); o[6] = f2bf(b.z); o[7] = f2bf(b.w);
    *(uint4*)dst = *(uint4*)o;
}

extern "C" void kernel_launch(void* const* d_in, const int* in_sizes, int n_in,
                              void* d_out, int out_size, void* d_ws, size_t ws_size,
                              hipStream_t stream)
{
    const float* x   = (const float*)d_in[0];
    const float* pos = (const float*)d_in[1];
    const float* Wq  = (const float*)d_in[2];
    const float* bq  = (const float*)d_in[3];
    const float* Wk  = (const float*)d_in[4];
    const float* bk  = (const float*)d_in[5];
    const float* Wv  = (const float*)d_in[6];
    const float* bv  = (const float*)d_in[7];
    const float* Wd  = (const float*)d_in[8];
    const float* bd  = (const float*)d_in[9];
    float* out = (float*)d_out;

    // workspace layout (bytes), total 153,092,096
    char* ws = (char*)d_ws;
    uint16_t* xb   = (uint16_t*)(ws);                 // 16,777,216  [16384,512]
    uint16_t* wqkv = (uint16_t*)(ws + 16777216);      //  1,572,864  [1536,512]
    uint16_t* wd   = (uint16_t*)(ws + 18350080);      //    524,288  [512,512]
    uint16_t* Qb   = (uint16_t*)(ws + 18874368);      // 16,777,216  [16384,512]
    uint16_t* Kb   = (uint16_t*)(ws + 35651584);      // 16,777,216  [16384,512]
    uint16_t* Vt   = (uint16_t*)(ws + 52428800);      // 16,777,216  [8,512,2048]
    uint16_t* Pb   = (uint16_t*)(ws + 69206016);      // 67,108,864  [8,2048,2048]
    uint16_t* yb   = (uint16_t*)(ws + 136314880);     // 16,777,216  [16384,512]

    prep_x<<<4096, 256, 0, stream>>>(x, pos, xb);
    prep_w<<<512, 256, 0, stream>>>(Wq, Wk, Wv, Wd, wqkv, wd);

    // Q|K|Vt = xb @ wqkv^T (+bias):  M=16384, N=1536, K=512
    // gm=128, gn=12 -> scols=3, stPerBatch=32*3=96, blocks=1536
    gemm_nt<3><<<1536, 256, 0, stream>>>(
        xb, wqkv, Qb, Kb, Vt, bq, bk, bv, 1.0f, 512, 512, 0, 0, 0, 3, 96);

    // P[b] = exp((Q[b] @ K[b]^T) * scale)  [unnormalized softmax numerator]
    // 8 x [2048,2048], K=512 -- 256^2 4-phase kernel (m201-ordered):
    // per batch gm=8, gn=8 -> scols=2, stPerBatch=4, blocks=512, 512 thr
    gemm_nt8<4><<<512, 512, 0, stream>>>(
        Qb, Kb, Pb, QK_SCALE, 512, 2048, (long)2048 * 512, (long)2048 * 512,
        (long)2048 * 2048, 2, 4);

    // y[b] = (P[b] @ Vt[b]^T) / rowsum(P[b]):  8 x [2048,512], K=2048
    // rowsum folded into PV (MODE 5).
    // per batch gm=16, gn=4 -> scols=1, stPerBatch=4, blocks=512
    gemm_nt<5><<<512, 256, 0, stream>>>(
        Pb, Vt, yb, nullptr, nullptr, nullptr, nullptr, nullptr,
        1.0f, 2048, 512, (long)2048 * 2048, (long)512 * 2048,
        (long)2048 * 512, 1, 4);

    // out = y @ wd^T + bd:  M=16384, N=512, K=512, fp32 out
    // gm=128, gn=4 -> scols=1, stPerBatch=32, blocks=512
    gemm_nt<2><<<512, 256, 0, stream>>>(
        yb, wd, out, nullptr, nullptr, bd, nullptr, nullptr,
        1.0f, 512, 512, 0, 0, 0, 1, 32);
}

// Round 4
// 263.652 us; speedup vs baseline: 1.0272x; 1.0272x over previous
//
#include <hip/hip_runtime.h>
#include <stdint.h>

typedef __bf16 bf16x8 __attribute__((ext_vector_type(8)));
typedef float f32x4 __attribute__((ext_vector_type(4)));

static constexpr float QK_SCALE = 0.044194173824159216f; // 1/sqrt(512)

__device__ __forceinline__ uint16_t f2bf(float f) {
    uint32_t x = __builtin_bit_cast(uint32_t, f);
    x += 0x7FFFu + ((x >> 16) & 1u);     // round-to-nearest-even; inputs finite
    return (uint16_t)(x >> 16);
}

// async 16B global->LDS copy (global_load_lds_dwordx4). LDS dest is
// wave-uniform base + lane*16; lds ptr = region_base + lane*16 matches.
__device__ __forceinline__ void cp16(const uint16_t* g, uint16_t* l) {
    __builtin_amdgcn_global_load_lds(
        (__attribute__((address_space(1))) void*)(uint16_t*)g,
        (__attribute__((address_space(3))) void*)l,
        16, 0, 0);
}

// ---------------------------------------------------------------------------
// NT GEMM: C[M,N] = A[M,K] * B[N,K]^T  (both K-contiguous, bf16)
// 128x128 block tile, BK=32, 256 thr = 4 waves (2x2), 64x64/wave.
// 3-stage circular LDS pipeline (3 x 16 KB = 48 KB) -> 3 blocks/CU.
// K-loop: RAW s_barrier + s_waitcnt vmcnt(4): stage k+1 and the just-issued
// k+2 stay in flight across the barrier. XOR-swizzled 16B chunks (0 bank
// conflicts, verified). XCD supertile swizzle. Tail prefetch clamps.
// MFMA operands swapped -> C^T layout -> packed dwordx2/x4 stores.
// MODE 0: bf16 out, batched, scale, no bias
// MODE 2: f32 out + bias0 (final projection)
// MODE 3: QKV split epilogue: n<512 -> Q, <1024 -> K, else V transposed
// MODE 5: bf16 out = acc / rowsum(A) (PV; softmax denominator folded in)
// ---------------------------------------------------------------------------
template <int MODE>
__global__ __launch_bounds__(256, 3) void gemm_nt(
    const uint16_t* __restrict__ A, const uint16_t* __restrict__ Bm,
    void* __restrict__ C0, void* __restrict__ C1, void* __restrict__ C2,
    const float* __restrict__ bias0, const float* __restrict__ bias1,
    const float* __restrict__ bias2,
    float scale, int K, int ldc, long bsA, long bsB, long bsC,
    int scols, int stPerBatch)
{
    // 3 stages x (A 128x32 | B 128x32) = 3 x 16 KB
    __shared__ __align__(16) uint16_t SH[3][8192];

    // --- supertile decode: id -> (bm, bn, bz) ------------------------------
    const uint32_t id  = blockIdx.x;
    const uint32_t xcd = id & 7u;
    const uint32_t p   = id >> 3;          // per-XCD sequence
    const uint32_t q   = p >> 4;           // local supertile index
    const uint32_t w   = p & 15u;          // position within 4x4 supertile
    const uint32_t g   = q * 8u + xcd;     // global supertile id
    const uint32_t bz  = g / (uint32_t)stPerBatch;
    const uint32_t gs  = g - bz * (uint32_t)stPerBatch;
    const uint32_t sr  = gs / (uint32_t)scols;
    const uint32_t sc  = gs - sr * (uint32_t)scols;
    const int bm = (int)(sr * 4u + (w >> 2));
    const int bn = (int)(sc * 4u + (w & 3u));
    // -----------------------------------------------------------------------

    const int t  = threadIdx.x;
    const int wave = t >> 6, lane = t & 63;
    const int wm = (wave >> 1) * 64, wn = (wave & 1) * 64;
    const int lm = lane & 15, lq = lane >> 4;
    const int sw = lq ^ ((lm >> 1) & 3);          // read-side swizzled k-group

    const uint16_t* Ab = A  + (long)bz * bsA + (long)bm * 128 * K;
    const uint16_t* Bb = Bm + (long)bz * bsB + (long)bn * 128 * K;

    // staging map (verified): slot s=j*256+t, row r=s>>2, slot col cs=s&3,
    // fetched k-group cg = cs ^ ((r>>1)&3); LDS addr = base + lane*16 (legal).
    long goff[2]; int loff[2];
#pragma unroll
    for (int j = 0; j < 2; ++j) {
        const int s  = j * 256 + t;
        const int r  = s >> 2;
        const int cs = s & 3;
        const int cg = cs ^ ((r >> 1) & 3);
        goff[j] = (long)r * K + cg * 8;
        loff[j] = s * 8;
    }

    const int KI = K >> 5;

    // prologue: stages 0,1 in flight (8 cp16/thread outstanding)
#pragma unroll
    for (int st = 0; st < 2; ++st)
#pragma unroll
        for (int j = 0; j < 2; ++j) {
            cp16(Ab + goff[j] + st * 32, SH[st] + loff[j]);
            cp16(Bb + goff[j] + st * 32, SH[st] + 4096 + loff[j]);
        }

    f32x4 acc[4][4] = {};
    float rsum[4] = {0.f, 0.f, 0.f, 0.f};         // MODE 5 only (else DCE'd)

    int cur = 0, pf = 2;                          // buf k%3, (k+2)%3
    for (int k = 0; k < KI; ++k) {
        asm volatile("s_waitcnt vmcnt(4) lgkmcnt(0)\n\ts_barrier" ::: "memory");

        int kp = k + 2; if (kp >= KI) kp = KI - 1; // tail: refetch hot tile
        uint16_t* dst = SH[pf];
        const long ko = (long)kp * 32;
#pragma unroll
        for (int j = 0; j < 2; ++j) {
            cp16(Ab + goff[j] + ko, dst + loff[j]);
            cp16(Bb + goff[j] + ko, dst + 4096 + loff[j]);
        }

        const uint16_t* buf = SH[cur];
        bf16x8 af[4], bfr[4];
#pragma unroll
        for (int i = 0; i < 4; ++i)               // A rows wm+i*16+lm
            af[i]  = *(const bf16x8*)&buf[((wm + i * 16 + lm) * 4 + sw) * 8];
#pragma unroll
        for (int i = 0; i < 4; ++i)               // B cols wn+i*16+lm
            bfr[i] = *(const bf16x8*)&buf[4096 + ((wn + i * 16 + lm) * 4 + sw) * 8];

        if (MODE == 5) {
            // rowsum of the A-fragments (bf16 -> f32 exact): this lane holds
            // rows wm+j*16+lm, k-slice sw*8..sw*8+7 of this K-step.
#pragma unroll
            for (int j = 0; j < 4; ++j) {
                const uint4 u = __builtin_bit_cast(uint4, af[j]);
                float s0 = __builtin_bit_cast(float, u.x << 16)
                         + __builtin_bit_cast(float, u.x & 0xFFFF0000u);
                float s1 = __builtin_bit_cast(float, u.y << 16)
                         + __builtin_bit_cast(float, u.y & 0xFFFF0000u);
                float s2 = __builtin_bit_cast(float, u.z << 16)
                         + __builtin_bit_cast(float, u.z & 0xFFFF0000u);
                float s3 = __builtin_bit_cast(float, u.w << 16)
                         + __builtin_bit_cast(float, u.w & 0xFFFF0000u);
                rsum[j] += (s0 + s1) + (s2 + s3);
            }
        }

#pragma unroll
        for (int i = 0; i < 4; ++i)
#pragma unroll
            for (int j = 0; j < 4; ++j)           // SWAPPED: D = C^T tile
                acc[i][j] = __builtin_amdgcn_mfma_f32_16x16x32_bf16(
                    bfr[i], af[j], acc[i][j], 0, 0, 0);

        cur = (cur == 2) ? 0 : cur + 1;
        pf  = (pf  == 2) ? 0 : pf  + 1;
    }

    // MODE 5: complete rowsum: lanes lm+16*lq (lq=0..3) hold disjoint
    // k-slices of the same A-row -> butterfly over lane bits 4,5.
    float inv[4];
    if (MODE == 5) {
#pragma unroll
        for (int j = 0; j < 4; ++j) {
            float s = rsum[j];
            s += __shfl_xor(s, 16);
            s += __shfl_xor(s, 32);
            inv[j] = 1.f / s;
        }
    }

    // epilogue: C^T layout -> lane holds n = nb+i*16+r (r=0..3 consecutive),
    // m = mb+j*16. Packed 8B/16B stores.
    const int mb = bm * 128 + wm + lm;
    const int nb = bn * 128 + wn + lq * 4;
#pragma unroll
    for (int i = 0; i < 4; ++i) {
        const int n = nb + i * 16;
        if (MODE == 0 || MODE == 5) {
#pragma unroll
            for (int j = 0; j < 4; ++j) {
                const int m = mb + j * 16;
                float v0, v1, v2, v3;
                if (MODE == 5) {                   // normalize by A-rowsum
                    v0 = acc[i][j][0] * inv[j];
                    v1 = acc[i][j][1] * inv[j];
                    v2 = acc[i][j][2] * inv[j];
                    v3 = acc[i][j][3] * inv[j];
                } else {
                    v0 = acc[i][j][0] * scale;
                    v1 = acc[i][j][1] * scale;
                    v2 = acc[i][j][2] * scale;
                    v3 = acc[i][j][3] * scale;
                }
                const uint32_t lo = (uint32_t)f2bf(v0) | ((uint32_t)f2bf(v1) << 16);
                const uint32_t hi = (uint32_t)f2bf(v2) | ((uint32_t)f2bf(v3) << 16);
                *(uint2*)&((uint16_t*)C0)[(long)bz * bsC + (long)m * ldc + n] =
                    make_uint2(lo, hi);
            }
        } else if (MODE == 2) {
            const float4 b4 = *(const float4*)&bias0[n];
#pragma unroll
            for (int j = 0; j < 4; ++j) {
                const int m = mb + j * 16;
                *(float4*)&((float*)C0)[(long)m * ldc + n] = make_float4(
                    acc[i][j][0] + b4.x, acc[i][j][1] + b4.y,
                    acc[i][j][2] + b4.z, acc[i][j][3] + b4.w);
            }
        } else { // MODE 3: whole block lives in one section (bn-uniform)
            const int sec = n >> 9, nn = n & 511;
            const float* bp = sec == 0 ? bias0 : (sec == 1 ? bias1 : bias2);
            const float4 b4 = *(const float4*)&bp[nn];
#pragma unroll
            for (int j = 0; j < 4; ++j) {
                const int m = mb + j * 16;
                if (sec < 2) {
                    uint16_t* Cq = (uint16_t*)(sec == 0 ? C0 : C1);
                    const uint32_t lo = (uint32_t)f2bf(acc[i][j][0] + b4.x) |
                                        ((uint32_t)f2bf(acc[i][j][1] + b4.y) << 16);
                    const uint32_t hi = (uint32_t)f2bf(acc[i][j][2] + b4.z) |
                                        ((uint32_t)f2bf(acc[i][j][3] + b4.w) << 16);
                    *(uint2*)&Cq[(long)m * 512 + nn] = make_uint2(lo, hi);
                } else { // V transposed: Vt[b][d][s], d = nn+r, s = m
                    const int bb = m >> 11, ss = m & 2047;
                    uint16_t* vt = (uint16_t*)C2 + ((long)bb * 512 + nn) * 2048 + ss;
                    vt[0]        = f2bf(acc[i][j][0] + b4.x);
                    vt[2048]     = f2bf(acc[i][j][1] + b4.y);
                    vt[2 * 2048] = f2bf(acc[i][j][2] + b4.z);
                    vt[3 * 2048] = f2bf(acc[i][j][3] + b4.w);
                }
            }
        }
    }
}

// ---------------------------------------------------------------------------
// R10: 256x256 / 8-wave NT GEMM, BARRIER-LIGHT (gemm_nt's proven schedule,
// scaled up). R8/R9 post-mortem: with 8 waves / 4 SIMDs, the per-phase MFMA
// island is only ~78 cyc while the phase read-burst drains ~600 cyc of LDS
// BW; barrier lockstep serializes them -> measured 4080 cyc/iter regardless
// of phase ordering. Fix: NO intra-iter barriers. One guard per K-iter
// (vmcnt(4)+lgkmcnt(0)+s_barrier), cp16s for stage k+2, then all 12 ds_reads
// issued back-to-back, then 4 setprio-wrapped MFMA clusters consuming the
// A-fragments in read order (compiler inserts progressive lgkm waits).
// LDS pipe streams continuously across wave skew; MFMA overlaps retirement.
// Correctness identical to gemm_nt: 4 cp16/thread/iter -> vmcnt(4) ==
// "stage k landed"; lgkmcnt(0)+barrier -> all reads of buf (k+2)%3 (from
// iter k-1) retired block-wide before its overwriting cp16s are issued.
// Epilogue: j-outer/i-inner so each row's 128B completes in 4 adjacent
// stores (fixes the 1.75x WRITE amplification from partial-line eviction).
// MODE 4: bf16 out = exp(acc*scale) (QK^T -> unnormalized P).
// ---------------------------------------------------------------------------
template <int MODE>
__global__ __launch_bounds__(512, 2) void gemm_nt8(
    const uint16_t* __restrict__ A, const uint16_t* __restrict__ Bm,
    void* __restrict__ C0,
    float scale, int K, int ldc, long bsA, long bsB, long bsC,
    int scols, int stPerBatch)
{
    // 3 stages x (A 256x32 | B 256x32) = 3 x 32 KB = 96 KB -> 1 block/CU
    __shared__ __align__(16) uint16_t SH[3][16384];

    // --- supertile decode (4x4 of 256^2 tiles), XCD-chunked ----------------
    const uint32_t id  = blockIdx.x;
    const uint32_t xcd = id & 7u;
    const uint32_t p   = id >> 3;
    const uint32_t q   = p >> 4;
    const uint32_t w   = p & 15u;
    const uint32_t g   = q * 8u + xcd;
    const uint32_t bz  = g / (uint32_t)stPerBatch;
    const uint32_t gs  = g - bz * (uint32_t)stPerBatch;
    const uint32_t sr  = gs / (uint32_t)scols;
    const uint32_t sc  = gs - sr * (uint32_t)scols;
    const int bm = (int)(sr * 4u + (w >> 2));
    const int bn = (int)(sc * 4u + (w & 3u));
    // -----------------------------------------------------------------------

    const int t  = threadIdx.x;
    const int wave = t >> 6, lane = t & 63;
    const int wm2 = (wave >> 2) * 128;            // row half   (0,128)
    const int wn2 = (wave & 3) * 64;              // col quarter(0..192)
    const int lm = lane & 15, lq = lane >> 4;
    const int sw = lq ^ ((lm >> 1) & 3);          // read-side swizzled k-group

    const uint16_t* Ab = A  + (long)bz * bsA + (long)bm * 256 * K;
    const uint16_t* Bb = Bm + (long)bz * bsB + (long)bn * 256 * K;

    // staging map (same verified XOR scheme, 256 rows x 4 chunks = 1024 slots
    // of 16B per operand, 512 threads -> 2 slots/thread/operand)
    long goff[2]; int loff[2];
#pragma unroll
    for (int j = 0; j < 2; ++j) {
        const int s  = j * 512 + t;
        const int r  = s >> 2;
        const int cs = s & 3;
        const int cg = cs ^ ((r >> 1) & 3);
        goff[j] = (long)r * K + cg * 8;
        loff[j] = s * 8;
    }

    const int KI = K >> 5;

    // prologue: stages 0,1 in flight (8 cp16/thread outstanding)
#pragma unroll
    for (int st = 0; st < 2; ++st)
#pragma unroll
        for (int j = 0; j < 2; ++j) {
            cp16(Ab + goff[j] + st * 32, SH[st] + loff[j]);
            cp16(Bb + goff[j] + st * 32, SH[st] + 8192 + loff[j]);
        }

    f32x4 acc[4][8] = {};

    int cur = 0, pf = 2;
    for (int k = 0; k < KI; ++k) {
        // stage k landed (oldest 4 of 8 outstanding retired); all my reads of
        // buf (k+2)%3 (iter k-1) retired; barrier extends both block-wide.
        asm volatile("s_waitcnt vmcnt(4) lgkmcnt(0)\n\ts_barrier" ::: "memory");

        int kp = k + 2; if (kp >= KI) kp = KI - 1; // tail: refetch hot tile
        uint16_t* dst = SH[pf];
        const long ko = (long)kp * 32;
#pragma unroll
        for (int j = 0; j < 2; ++j) {
            cp16(Ab + goff[j] + ko, dst + loff[j]);
            cp16(Bb + goff[j] + ko, dst + 8192 + loff[j]);
        }

        const uint16_t* buf = SH[cur];
        bf16x8 af[8], bfr[4];
#define RDA(jj) (*(const bf16x8*)&buf[((wm2 + (jj) * 16 + lm) * 4 + sw) * 8])
#define RDB(ii) (*(const bf16x8*)&buf[8192 + ((wn2 + (ii) * 16 + lm) * 4 + sw) * 8])
        // issue all 12 reads back-to-back (B first, then A in consume order)
        bfr[0] = RDB(0); bfr[1] = RDB(1); bfr[2] = RDB(2); bfr[3] = RDB(3);
        af[0] = RDA(0); af[1] = RDA(1); af[2] = RDA(2); af[3] = RDA(3);
        af[4] = RDA(4); af[5] = RDA(5); af[6] = RDA(6); af[7] = RDA(7);
        // 4 MFMA clusters consume af pairs in read order; compiler inserts
        // progressive lgkm waits so later reads stay in flight under MFMA.
#pragma unroll
        for (int pp = 0; pp < 4; ++pp) {
            __builtin_amdgcn_s_setprio(1);
#pragma unroll
            for (int i = 0; i < 4; ++i) {
                acc[i][2 * pp]     = __builtin_amdgcn_mfma_f32_16x16x32_bf16(
                    bfr[i], af[2 * pp],     acc[i][2 * pp],     0, 0, 0);
                acc[i][2 * pp + 1] = __builtin_amdgcn_mfma_f32_16x16x32_bf16(
                    bfr[i], af[2 * pp + 1], acc[i][2 * pp + 1], 0, 0, 0);
            }
            __builtin_amdgcn_s_setprio(0);
        }
#undef RDA
#undef RDB

        cur = (cur == 2) ? 0 : cur + 1;
        pf  = (pf  == 2) ? 0 : pf  + 1;
    }

    // epilogue: C^T layout; m = row (lane&15 based), n = col (lq*4+reg based)
    // j-outer/i-inner: each row's 128B span completes in 4 adjacent stores.
    const int mb = bm * 256 + wm2 + lm;
    const int nb = bn * 256 + wn2 + lq * 4;
#pragma unroll
    for (int j = 0; j < 8; ++j) {
        const int m = mb + j * 16;
#pragma unroll
        for (int i = 0; i < 4; ++i) {
            const int n = nb + i * 16;
            float v0, v1, v2, v3;
            if (MODE == 4) {                       // unnormalized softmax num.
                v0 = __expf(acc[i][j][0] * scale);
                v1 = __expf(acc[i][j][1] * scale);
                v2 = __expf(acc[i][j][2] * scale);
                v3 = __expf(acc[i][j][3] * scale);
            } else {
                v0 = acc[i][j][0] * scale; v1 = acc[i][j][1] * scale;
                v2 = acc[i][j][2] * scale; v3 = acc[i][j][3] * scale;
            }
            const uint32_t lo = (uint32_t)f2bf(v0) | ((uint32_t)f2bf(v1) << 16);
            const uint32_t hi = (uint32_t)f2bf(v2) | ((uint32_t)f2bf(v3) << 16);
            *(uint2*)&((uint16_t*)C0)[(long)bz * bsC + (long)m * ldc + n] =
                make_uint2(lo, hi);
        }
    }
}

// x + pos_table -> bf16, 8 elems/thread, exact grid (4096 blocks)
__global__ __launch_bounds__(256) void prep_x(const float* __restrict__ x,
                                              const float* __restrict__ pos,
                                              uint16_t* __restrict__ xb)
{
    const long i8 = ((long)blockIdx.x * 256 + threadIdx.x) * 8;
    const long p8 = i8 & ((1l << 20) - 1);   // S*D = 2^20
    const float4* xv = (const float4*)(x + i8);
    const float4* pv = (const float4*)(pos + p8);
    const float4 a0 = xv[0], a1 = xv[1];
    const float4 b0 = pv[0], b1 = pv[1];
    uint16_t o[8];
    o[0] = f2bf(a0.x + b0.x); o[1] = f2bf(a0.y + b0.y);
    o[2] = f2bf(a0.z + b0.z); o[3] = f2bf(a0.w + b0.w);
    o[4] = f2bf(a1.x + b1.x); o[5] = f2bf(a1.y + b1.y);
    o[6] = f2bf(a1.z + b1.z); o[7] = f2bf(a1.w + b1.w);
    *(uint4*)(xb + i8) = *(uint4*)o;
}

// Wq,Wk,Wv -> stacked wqkv[1536,512] bf16; Wd -> wd bf16. 512 blocks exact.
__global__ __launch_bounds__(256) void prep_w(
    const float* __restrict__ Wq, const float* __restrict__ Wk,
    const float* __restrict__ Wv, const float* __restrict__ Wd,
    uint16_t* __restrict__ wqkv, uint16_t* __restrict__ wd)
{
    const long f = ((long)blockIdx.x * 256 + threadIdx.x) * 8;
    const int  w = (int)(f >> 18);          // 262144 elems per weight
    const long off = f & 262143;
    const float* src = (w == 0) ? Wq : (w == 1) ? Wk : (w == 2) ? Wv : Wd;
    uint16_t* dst = (w < 3) ? (wqkv + (long)w * 262144 + off) : (wd + off);
    const float4* s4 = (const float4*)(src + off);
    const float4 a = s4[0], b = s4[1];
    uint16_t o[8];
    o[0] = f2bf(a.x); o[1] = f2bf(a.y); o[2] = f2bf(a.z); o[3] = f2bf(a.w);
    o[4] = f2bf(b.x); o[5] = f2bf(b.y); o[6] = f2bf(b.z); o[7] = f2bf(b.w);
    *(uint4*)dst = *(uint4*)o;
}

extern "C" void kernel_launch(void* const* d_in, const int* in_sizes, int n_in,
                              void* d_out, int out_size, void* d_ws, size_t ws_size,
                              hipStream_t stream)
{
    const float* x   = (const float*)d_in[0];
    const float* pos = (const float*)d_in[1];
    const float* Wq  = (const float*)d_in[2];
    const float* bq  = (const float*)d_in[3];
    const float* Wk  = (const float*)d_in[4];
    const float* bk  = (const float*)d_in[5];
    const float* Wv  = (const float*)d_in[6];
    const float* bv  = (const float*)d_in[7];
    const float* Wd  = (const float*)d_in[8];
    const float* bd  = (const float*)d_in[9];
    float* out = (float*)d_out;

    // workspace layout (bytes), total 153,092,096
    char* ws = (char*)d_ws;
    uint16_t* xb   = (uint16_t*)(ws);                 // 16,777,216  [16384,512]
    uint16_t* wqkv = (uint16_t*)(ws + 16777216);      //  1,572,864  [1536,512]
    uint16_t* wd   = (uint16_t*)(ws + 18350080);      //    524,288  [512,512]
    uint16_t* Qb   = (uint16_t*)(ws + 18874368);      // 16,777,216  [16384,512]
    uint16_t* Kb   = (uint16_t*)(ws + 35651584);      // 16,777,216  [16384,512]
    uint16_t* Vt   = (uint16_t*)(ws + 52428800);      // 16,777,216  [8,512,2048]
    uint16_t* Pb   = (uint16_t*)(ws + 69206016);      // 67,108,864  [8,2048,2048]
    uint16_t* yb   = (uint16_t*)(ws + 136314880);     // 16,777,216  [16384,512]

    prep_x<<<4096, 256, 0, stream>>>(x, pos, xb);
    prep_w<<<512, 256, 0, stream>>>(Wq, Wk, Wv, Wd, wqkv, wd);

    // Q|K|Vt = xb @ wqkv^T (+bias):  M=16384, N=1536, K=512
    // gm=128, gn=12 -> scols=3, stPerBatch=32*3=96, blocks=1536
    gemm_nt<3><<<1536, 256, 0, stream>>>(
        xb, wqkv, Qb, Kb, Vt, bq, bk, bv, 1.0f, 512, 512, 0, 0, 0, 3, 96);

    // P[b] = exp((Q[b] @ K[b]^T) * scale)  [unnormalized softmax numerator]
    // 8 x [2048,2048], K=512 -- 256^2 barrier-light kernel:
    // per batch gm=8, gn=8 -> scols=2, stPerBatch=4, blocks=512, 512 thr
    gemm_nt8<4><<<512, 512, 0, stream>>>(
        Qb, Kb, Pb, QK_SCALE, 512, 2048, (long)2048 * 512, (long)2048 * 512,
        (long)2048 * 2048, 2, 4);

    // y[b] = (P[b] @ Vt[b]^T) / rowsum(P[b]):  8 x [2048,512], K=2048
    // rowsum folded into PV (MODE 5).
    // per batch gm=16, gn=4 -> scols=1, stPerBatch=4, blocks=512
    gemm_nt<5><<<512, 256, 0, stream>>>(
        Pb, Vt, yb, nullptr, nullptr, nullptr, nullptr, nullptr,
        1.0f, 2048, 512, (long)2048 * 2048, (long)512 * 2048,
        (long)2048 * 512, 1, 4);

    // out = y @ wd^T + bd:  M=16384, N=512, K=512, fp32 out
    // gm=128, gn=4 -> scols=1, stPerBatch=32, blocks=512
    gemm_nt<2><<<512, 256, 0, stream>>>(
        yb, wd, out, nullptr, nullptr, bd, nullptr, nullptr,
        1.0f, 512, 512, 0, 0, 0, 1, 32);
}